// Round 13
// baseline (111.364 us; speedup 1.0000x reference)
//
#include <hip/hip_runtime.h>
#include <math.h>

// Problem constants
#define B 2
#define N 8192            // points per batch
#define PTS_STRIDE (N*3)
#define VOXEL 0.1f

#define CBLK 128          // chamfer: 2 waves per block
#define PBLK 1024

// ws layout (float offsets); ws_size >= 17 MB known, we use ~4.3 MB.
//  [0..3] 16B zero block (A-frag source for k>=16 lanes)
//  [16] acc   [17] ticket   [20..31] gmin[g][3]
//  OFF_PACK per g=arr*2+b (PERG=147456 floats):
//    AFLO[N] short8: [y0,y1,y2,yyh,yyl,w0,w1,w2]   (A rows, k=0..7)
//    AFHI[N] short8: [vvh,vvl,0,...]               (A rows, k=8..15)
//    BR[N]   short8: [-2x0,-2x1,-2x2,1,1,0,0,0]    (B raw col, k=0..7)
//    BV[N]   short8: [0,0,0,0,0,-2u0,-2u1,-2u2]    (B vox col, k=0..7)
//    XXR[N], XXV[N] f32
//  OFF_PART: float part[ysub(8)][slot(4)][var(2)][x(8192)] = 2 MB, single writer per cell
#define WS_ZERO 0
#define WS_ACC 16
#define WS_TICKET 17
#define WS_GMIN 20
#define OFF_PACK 32
#define PERG 147456
#define OFF_AFLO(g) (OFF_PACK + (g)*PERG)
#define OFF_AFHI(g) (OFF_AFLO(g) + 32768)
#define OFF_BR(g)   (OFF_AFLO(g) + 65536)
#define OFF_BV(g)   (OFF_AFLO(g) + 98304)
#define OFF_XXR(g)  (OFF_AFLO(g) + 131072)
#define OFF_XXV(g)  (OFF_AFLO(g) + 139264)
#define OFF_PART    (OFF_PACK + 4*PERG)
#define PART_IDX(ys, slot, var, x) (OFF_PART + (((((ys)*4 + (slot))*2 + (var)) << 13)) + (x))

typedef __attribute__((ext_vector_type(8))) short short8;    // 8 bf16 (MFMA A/B frag)
typedef __attribute__((ext_vector_type(4))) float f4;        // 16x16 MFMA C/D frag

union S8 { short8 v; unsigned short u[8]; };

__device__ __forceinline__ unsigned short f2bf(float f) {    // RNE f32->bf16
    unsigned u = __float_as_uint(f);
    return (unsigned short)((u + 0x7FFFu + ((u >> 16) & 1u)) >> 16);
}
__device__ __forceinline__ float bf2f(unsigned short h) {
    return __uint_as_float(((unsigned)h) << 16);
}
__device__ __forceinline__ float voxq(float v, float g) {
    return (float)(int)((v - g) / VOXEL);   // trunc like .astype(int32)
}

// 4 blocks (one per g=arr*2+b): per-batch coordinate min, vectorized.
__global__ void __launch_bounds__(PBLK)
gmin_kernel(const float* __restrict__ preds,
            const float* __restrict__ gts,
            float* __restrict__ ws) {
    const int g   = blockIdx.x;
    const int arr = g >> 1;
    const int b   = g & 1;
    const float4* base4 = (const float4*)((arr ? gts : preds) + b * PTS_STRIDE);

    float m0 = INFINITY, m1 = INFINITY, m2 = INFINITY;
#pragma unroll
    for (int j = 0; j < 2; ++j) {
        const int i = j * PBLK + threadIdx.x;     // 0..2047, 4 points each
        const float4 q0 = base4[i*3+0];   // p0x p0y p0z p1x
        const float4 q1 = base4[i*3+1];   // p1y p1z p2x p2y
        const float4 q2 = base4[i*3+2];   // p2z p3x p3y p3z
        float v;
        v = q0.x; m0 = fminf(m0, (v!=v)?INFINITY:v);
        v = q0.w; m0 = fminf(m0, (v!=v)?INFINITY:v);
        v = q1.z; m0 = fminf(m0, (v!=v)?INFINITY:v);
        v = q2.y; m0 = fminf(m0, (v!=v)?INFINITY:v);
        v = q0.y; m1 = fminf(m1, (v!=v)?INFINITY:v);
        v = q1.x; m1 = fminf(m1, (v!=v)?INFINITY:v);
        v = q1.w; m1 = fminf(m1, (v!=v)?INFINITY:v);
        v = q2.z; m1 = fminf(m1, (v!=v)?INFINITY:v);
        v = q0.z; m2 = fminf(m2, (v!=v)?INFINITY:v);
        v = q1.y; m2 = fminf(m2, (v!=v)?INFINITY:v);
        v = q2.x; m2 = fminf(m2, (v!=v)?INFINITY:v);
        v = q2.w; m2 = fminf(m2, (v!=v)?INFINITY:v);
    }
    for (int off = 32; off; off >>= 1) {
        m0 = fminf(m0, __shfl_down(m0, off));
        m1 = fminf(m1, __shfl_down(m1, off));
        m2 = fminf(m2, __shfl_down(m2, off));
    }
    __shared__ float sm[16][3];
    const int wave = threadIdx.x >> 6, lane = threadIdx.x & 63;
    if (lane == 0) { sm[wave][0] = m0; sm[wave][1] = m1; sm[wave][2] = m2; }
    __syncthreads();
    if (threadIdx.x == 0) {
        float a0 = sm[0][0], a1 = sm[0][1], a2 = sm[0][2];
        for (int w = 1; w < 16; ++w) {
            a0 = fminf(a0, sm[w][0]);
            a1 = fminf(a1, sm[w][1]);
            a2 = fminf(a2, sm[w][2]);
        }
        ws[WS_GMIN + g*3+0] = a0; ws[WS_GMIN + g*3+1] = a1; ws[WS_GMIN + g*3+2] = a2;
        if (g == 0) {
            ws[WS_ACC] = 0.0f; ((unsigned*)ws)[WS_TICKET] = 0u;
            ws[WS_ZERO+0] = 0.0f; ws[WS_ZERO+1] = 0.0f;
            ws[WS_ZERO+2] = 0.0f; ws[WS_ZERO+3] = 0.0f;   // 16B zero A-frag
        }
    }
}

// One thread per point (128 blocks x 256 = 32768): build all fragments.
__global__ void __launch_bounds__(256)
pack_kernel(const float* __restrict__ preds,
            const float* __restrict__ gts,
            float* __restrict__ ws) {
    const int i   = blockIdx.x * 256 + threadIdx.x;   // 0..32767
    const int g   = i >> 13;
    const int idx = i & (N-1);
    const int arr = g >> 1;
    const int b   = g & 1;
    const float* base = (arr ? gts : preds) + b * PTS_STRIDE;

    const float g0 = ws[WS_GMIN + g*3+0];
    const float g1 = ws[WS_GMIN + g*3+1];
    const float g2 = ws[WS_GMIN + g*3+2];

    const float p0 = base[idx*3+0], p1 = base[idx*3+1], p2 = base[idx*3+2];
    const float w0 = voxq(p0, g0), w1 = voxq(p1, g1), w2 = voxq(p2, g2);
    const float rr = fmaf(p0,p0, fmaf(p1,p1, p2*p2));
    const float vv = fmaf(w0,w0, fmaf(w1,w1, w2*w2));

    const unsigned short yyh = f2bf(rr);
    const unsigned short yyl = f2bf(rr - bf2f(yyh));
    const unsigned short vvh = f2bf(vv);
    const unsigned short vvl = f2bf(vv - bf2f(vvh));
    const unsigned short ONE = 0x3F80;

    short8* AFLO = (short8*)(ws + OFF_AFLO(g));
    short8* AFHI = (short8*)(ws + OFF_AFHI(g));
    short8* BR   = (short8*)(ws + OFF_BR(g));
    short8* BV   = (short8*)(ws + OFF_BV(g));

    S8 f;
    // A lo (k=0..7): [y0,y1,y2,yyh,yyl, w0,w1,w2]
    f.u[0]=f2bf(p0); f.u[1]=f2bf(p1); f.u[2]=f2bf(p2);
    f.u[3]=yyh; f.u[4]=yyl; f.u[5]=f2bf(w0); f.u[6]=f2bf(w1); f.u[7]=f2bf(w2);
    AFLO[idx] = f.v;
    // A hi (k=8..15): [vvh,vvl,0...]
    f.u[0]=vvh; f.u[1]=vvl; f.u[2]=0; f.u[3]=0; f.u[4]=0; f.u[5]=0; f.u[6]=0; f.u[7]=0;
    AFHI[idx] = f.v;
    // B raw col (k=0..7): [-2x, 1,1, 0,0,0]
    f.u[0]=f2bf(-2.0f*p0); f.u[1]=f2bf(-2.0f*p1); f.u[2]=f2bf(-2.0f*p2);
    f.u[3]=ONE; f.u[4]=ONE; f.u[5]=0; f.u[6]=0; f.u[7]=0;
    BR[idx] = f.v;
    // B vox col (k=0..7): [0,0,0,0,0, -2u]
    f.u[0]=0; f.u[1]=0; f.u[2]=0; f.u[3]=0; f.u[4]=0;
    f.u[5]=f2bf(-2.0f*w0); f.u[6]=f2bf(-2.0f*w1); f.u[7]=f2bf(-2.0f*w2);
    BV[idx] = f.v;
    ws[OFF_XXR(g) + idx] = rr;
    ws[OFF_XXV(g) + idx] = vv;
}

// Chamfer, 16x16x32 MFMA (4-reg C/D => low VGPR pressure, 8 waves/SIMD):
// A rows = 16 y: lane m=lane&15, quad q=lane>>4 selects k-range
//   q0 -> AFLO[y] (k0..7), q1 -> AFHI[y] (k8..15), q2/q3 -> 16B zero block.
// B cols = 8 x * 2 variants per chain: n=lane&15; n<8 raw x_n, n>=8 vox x_{n-8};
//   q0: BR/BV, q1: [1,1,0..] for vox cols only, q2/q3 zero.
// 4 chains cover 32 x. Per iter: 1 A-load + 4 MFMA + ~16 v_min.
// Grid 4096 blocks (256 xtiles x 4 ypairs x 4 slots) x 128 thr; ysub = y*2+wave.
__global__ void __launch_bounds__(CBLK)
chamfer_kernel(float* __restrict__ ws) {
    const int tid  = threadIdx.x;
    const int wave = tid >> 6, lane = tid & 63;
    const int q    = lane >> 4, n = lane & 15;
    const int slot = blockIdx.z;           // 0..3
    const int dir  = slot & 1;
    const int b    = slot >> 1;
    const int gX = dir*2 + b;
    const int gY = (1-dir)*2 + b;

    const short8* AFLO = (const short8*)(ws + OFF_AFLO(gY));
    const short8* AFHI = (const short8*)(ws + OFF_AFHI(gY));
    const short8* ZB   = (const short8*)(ws + WS_ZERO);
    const short8* BR   = (const short8*)(ws + OFF_BR(gX));
    const short8* BV   = (const short8*)(ws + OFF_BV(gX));

    // B-frags for 4 chains (8 x each; cols n<8 raw, n>=8 vox)
    const int xbase = blockIdx.x * 32;
    S8 onef;   // q1 frag for vox cols: k8,k9 = 1.0 (multiplies vvh,vvl)
    onef.u[0]=0x3F80; onef.u[1]=0x3F80;
    onef.u[2]=0; onef.u[3]=0; onef.u[4]=0; onef.u[5]=0; onef.u[6]=0; onef.u[7]=0;
    const short8 zf = *ZB;                 // zero frag (16B broadcast)
    short8 bf[4];
#pragma unroll
    for (int f = 0; f < 4; ++f) {
        const int xi = xbase + f*8 + (n & 7);
        short8 v = zf;
        if (q == 0) v = (n < 8) ? BR[xi] : BV[xi];
        else if (q == 1 && n >= 8) v = onef.v;
        bf[f] = v;
    }

    // per-lane A pointer: q0->AFLO, q1->AFHI, q2/3->zero block (stride 0)
    const int ysub = blockIdx.y * 2 + wave;          // 0..7
    const int y0 = ysub * 1024 + n;
    const short8* aptr = (q == 0) ? (AFLO + y0) : (q == 1) ? (AFHI + y0) : ZB;
    const int astep = (q < 2) ? 16 : 0;

    f4 Z = (f4){0.f, 0.f, 0.f, 0.f};
    float a0 = INFINITY, a1 = INFINITY, a2 = INFINITY, a3 = INFINITY;

#pragma unroll 4
    for (int t = 0; t < 64; ++t) {         // 64 y-tiles of 16
        const short8 a = *aptr; aptr += astep;
        const f4 d0 = __builtin_amdgcn_mfma_f32_16x16x32_bf16(a, bf[0], Z, 0, 0, 0);
        a0 = fminf(a0, fminf(fminf(d0[0], d0[1]), fminf(d0[2], d0[3])));
        const f4 d1 = __builtin_amdgcn_mfma_f32_16x16x32_bf16(a, bf[1], Z, 0, 0, 0);
        a1 = fminf(a1, fminf(fminf(d1[0], d1[1]), fminf(d1[2], d1[3])));
        const f4 d2 = __builtin_amdgcn_mfma_f32_16x16x32_bf16(a, bf[2], Z, 0, 0, 0);
        a2 = fminf(a2, fminf(fminf(d2[0], d2[1]), fminf(d2[2], d2[3])));
        const f4 d3 = __builtin_amdgcn_mfma_f32_16x16x32_bf16(a, bf[3], Z, 0, 0, 0);
        a3 = fminf(a3, fminf(fminf(d3[0], d3[1]), fminf(d3[2], d3[3])));
    }

    // fold across quads (each lane's acc covers rows q*4..q*4+3 of col n)
    a0 = fminf(a0, __shfl_xor(a0, 16)); a0 = fminf(a0, __shfl_xor(a0, 32));
    a1 = fminf(a1, __shfl_xor(a1, 16)); a1 = fminf(a1, __shfl_xor(a1, 32));
    a2 = fminf(a2, __shfl_xor(a2, 16)); a2 = fminf(a2, __shfl_xor(a2, 32));
    a3 = fminf(a3, __shfl_xor(a3, 16)); a3 = fminf(a3, __shfl_xor(a3, 32));

    if (q == 0) {
        // single writer per cell: plain stores (8-consecutive-x groups)
        const int var = (n < 8) ? 0 : 1;
        const int xr  = xbase + (n & 7);
        ws[PART_IDX(ysub, slot, var, xr)]      = a0;
        ws[PART_IDX(ysub, slot, var, xr + 8)]  = a1;
        ws[PART_IDX(ysub, slot, var, xr + 16)] = a2;
        ws[PART_IDX(ysub, slot, var, xr + 24)] = a3;
    }
}

// 128 blocks x 256: one thread per (slot,x). Fold 8 ysubs, add |x|^2, sum, ticket-out.
__global__ void __launch_bounds__(256)
finalize_kernel(float* __restrict__ ws, float* __restrict__ out) {
    const int g = blockIdx.x * 256 + threadIdx.x;   // 0..32767
    const int slot = g >> 13;
    const int x    = g & (N-1);
    const int dir  = slot & 1;
    const int b    = slot >> 1;
    const int gX   = dir*2 + b;
    float m_r = INFINITY, m_v = INFINITY;
#pragma unroll
    for (int ys = 0; ys < 8; ++ys) {
        m_r = fminf(m_r, ws[PART_IDX(ys, slot, 0, x)]);
        m_v = fminf(m_v, ws[PART_IDX(ys, slot, 1, x)]);
    }
    float s = m_r + ws[OFF_XXR(gX) + x] + m_v + ws[OFF_XXV(gX) + x];
    for (int off = 32; off; off >>= 1)
        s += __shfl_down(s, off);
    __shared__ float sm[4];
    const int wave = threadIdx.x >> 6, lane = threadIdx.x & 63;
    if (lane == 0) sm[wave] = s;
    __syncthreads();
    if (threadIdx.x == 0) {
        const float bs = sm[0] + sm[1] + sm[2] + sm[3];
        atomicAdd(ws + WS_ACC, bs);
        __threadfence();
        const unsigned t = atomicAdd(&((unsigned*)ws)[WS_TICKET], 1u);
        if (t == gridDim.x - 1) {
            __threadfence();
            const float total = atomicAdd(ws + WS_ACC, 0.0f);  // atomic read
            out[0] = total * (1.0f / 16384.0f);
        }
    }
}

extern "C" void kernel_launch(void* const* d_in, const int* in_sizes, int n_in,
                              void* d_out, int out_size, void* d_ws, size_t ws_size,
                              hipStream_t stream) {
    const float* preds = (const float*)d_in[0];
    const float* gts   = (const float*)d_in[1];
    float* ws  = (float*)d_ws;
    float* out = (float*)d_out;

    gmin_kernel<<<dim3(4), dim3(PBLK), 0, stream>>>(preds, gts, ws);
    pack_kernel<<<dim3(128), dim3(256), 0, stream>>>(preds, gts, ws);
    chamfer_kernel<<<dim3(N/32, 4, 4), dim3(CBLK), 0, stream>>>(ws);
    finalize_kernel<<<dim3(128), dim3(256), 0, stream>>>(ws, out);
}

// Round 14
// 96.227 us; speedup vs baseline: 1.1573x; 1.1573x over previous
//
#include <hip/hip_runtime.h>
#include <math.h>

// Problem constants
#define B 2
#define N 8192            // points per batch
#define PTS_STRIDE (N*3)
#define VOXEL 0.1f

#define CBLK 128          // chamfer: 2 waves per block
#define PBLK 1024

// ws layout (float offsets); ws_size >= 17 MB known, we use ~4.3 MB.
//  [16] acc   [17] ticket   [20..31] gmin[g][3]
//  OFF_PACK per g=arr*2+b (PERG=147456 floats):
//    AFLO[N] short8: [y0,y1,y2,yyh,yyl,w0,w1,w2]   (A rows, k=0..7)
//    AFHI[N] short8: [vvh,vvl,0,...]               (A rows, k=8..15)
//    BR[N]   short8: [-2x0,-2x1,-2x2,1,1,0,0,0]    (B raw col, k=0..7)
//    BV[N]   short8: [0,0,0,0,0,-2u0,-2u1,-2u2]    (B vox col, k=0..7)
//    XXR[N], XXV[N] f32
//  OFF_PART: float part[ysub(8)][slot(4)][var(2)][x(8192)] = 2 MB, single writer per cell
#define WS_ACC 16
#define WS_TICKET 17
#define WS_GMIN 20
#define OFF_PACK 32
#define PERG 147456
#define OFF_AFLO(g) (OFF_PACK + (g)*PERG)
#define OFF_AFHI(g) (OFF_AFLO(g) + 32768)
#define OFF_BR(g)   (OFF_AFLO(g) + 65536)
#define OFF_BV(g)   (OFF_AFLO(g) + 98304)
#define OFF_XXR(g)  (OFF_AFLO(g) + 131072)
#define OFF_XXV(g)  (OFF_AFLO(g) + 139264)
#define OFF_PART    (OFF_PACK + 4*PERG)
#define PART_IDX(ys, slot, var, x) (OFF_PART + (((((ys)*4 + (slot))*2 + (var)) << 13)) + (x))

typedef __attribute__((ext_vector_type(8))) short short8;    // 8 bf16 (MFMA A/B frag)
typedef __attribute__((ext_vector_type(16))) float f16v;     // 32x32 MFMA C/D frag

union S8 { short8 v; unsigned short u[8]; };

__device__ __forceinline__ unsigned short f2bf(float f) {    // RNE f32->bf16
    unsigned u = __float_as_uint(f);
    return (unsigned short)((u + 0x7FFFu + ((u >> 16) & 1u)) >> 16);
}
__device__ __forceinline__ float bf2f(unsigned short h) {
    return __uint_as_float(((unsigned)h) << 16);
}
__device__ __forceinline__ float voxq(float v, float g) {
    return (float)(int)((v - g) / VOXEL);   // trunc like .astype(int32)
}

// 4 blocks (one per g=arr*2+b): per-batch coordinate min, vectorized.
__global__ void __launch_bounds__(PBLK)
gmin_kernel(const float* __restrict__ preds,
            const float* __restrict__ gts,
            float* __restrict__ ws) {
    const int g   = blockIdx.x;
    const int arr = g >> 1;
    const int b   = g & 1;
    const float4* base4 = (const float4*)((arr ? gts : preds) + b * PTS_STRIDE);

    float m0 = INFINITY, m1 = INFINITY, m2 = INFINITY;
#pragma unroll
    for (int j = 0; j < 2; ++j) {
        const int i = j * PBLK + threadIdx.x;     // 0..2047, 4 points each
        const float4 q0 = base4[i*3+0];   // p0x p0y p0z p1x
        const float4 q1 = base4[i*3+1];   // p1y p1z p2x p2y
        const float4 q2 = base4[i*3+2];   // p2z p3x p3y p3z
        float v;
        v = q0.x; m0 = fminf(m0, (v!=v)?INFINITY:v);
        v = q0.w; m0 = fminf(m0, (v!=v)?INFINITY:v);
        v = q1.z; m0 = fminf(m0, (v!=v)?INFINITY:v);
        v = q2.y; m0 = fminf(m0, (v!=v)?INFINITY:v);
        v = q0.y; m1 = fminf(m1, (v!=v)?INFINITY:v);
        v = q1.x; m1 = fminf(m1, (v!=v)?INFINITY:v);
        v = q1.w; m1 = fminf(m1, (v!=v)?INFINITY:v);
        v = q2.z; m1 = fminf(m1, (v!=v)?INFINITY:v);
        v = q0.z; m2 = fminf(m2, (v!=v)?INFINITY:v);
        v = q1.y; m2 = fminf(m2, (v!=v)?INFINITY:v);
        v = q2.x; m2 = fminf(m2, (v!=v)?INFINITY:v);
        v = q2.w; m2 = fminf(m2, (v!=v)?INFINITY:v);
    }
    for (int off = 32; off; off >>= 1) {
        m0 = fminf(m0, __shfl_down(m0, off));
        m1 = fminf(m1, __shfl_down(m1, off));
        m2 = fminf(m2, __shfl_down(m2, off));
    }
    __shared__ float sm[16][3];
    const int wave = threadIdx.x >> 6, lane = threadIdx.x & 63;
    if (lane == 0) { sm[wave][0] = m0; sm[wave][1] = m1; sm[wave][2] = m2; }
    __syncthreads();
    if (threadIdx.x == 0) {
        float a0 = sm[0][0], a1 = sm[0][1], a2 = sm[0][2];
        for (int w = 1; w < 16; ++w) {
            a0 = fminf(a0, sm[w][0]);
            a1 = fminf(a1, sm[w][1]);
            a2 = fminf(a2, sm[w][2]);
        }
        ws[WS_GMIN + g*3+0] = a0; ws[WS_GMIN + g*3+1] = a1; ws[WS_GMIN + g*3+2] = a2;
        if (g == 0) { ws[WS_ACC] = 0.0f; ((unsigned*)ws)[WS_TICKET] = 0u; }
    }
}

// One thread per point (128 blocks x 256 = 32768): build all fragments.
__global__ void __launch_bounds__(256)
pack_kernel(const float* __restrict__ preds,
            const float* __restrict__ gts,
            float* __restrict__ ws) {
    const int i   = blockIdx.x * 256 + threadIdx.x;   // 0..32767
    const int g   = i >> 13;
    const int idx = i & (N-1);
    const int arr = g >> 1;
    const int b   = g & 1;
    const float* base = (arr ? gts : preds) + b * PTS_STRIDE;

    const float g0 = ws[WS_GMIN + g*3+0];
    const float g1 = ws[WS_GMIN + g*3+1];
    const float g2 = ws[WS_GMIN + g*3+2];

    const float p0 = base[idx*3+0], p1 = base[idx*3+1], p2 = base[idx*3+2];
    const float w0 = voxq(p0, g0), w1 = voxq(p1, g1), w2 = voxq(p2, g2);
    const float rr = fmaf(p0,p0, fmaf(p1,p1, p2*p2));
    const float vv = fmaf(w0,w0, fmaf(w1,w1, w2*w2));

    const unsigned short yyh = f2bf(rr);
    const unsigned short yyl = f2bf(rr - bf2f(yyh));
    const unsigned short vvh = f2bf(vv);
    const unsigned short vvl = f2bf(vv - bf2f(vvh));
    const unsigned short ONE = 0x3F80;

    short8* AFLO = (short8*)(ws + OFF_AFLO(g));
    short8* AFHI = (short8*)(ws + OFF_AFHI(g));
    short8* BR   = (short8*)(ws + OFF_BR(g));
    short8* BV   = (short8*)(ws + OFF_BV(g));

    S8 f;
    // A lo (k=0..7): [y0,y1,y2,yyh,yyl, w0,w1,w2]
    f.u[0]=f2bf(p0); f.u[1]=f2bf(p1); f.u[2]=f2bf(p2);
    f.u[3]=yyh; f.u[4]=yyl; f.u[5]=f2bf(w0); f.u[6]=f2bf(w1); f.u[7]=f2bf(w2);
    AFLO[idx] = f.v;
    // A hi (k=8..15): [vvh,vvl,0...]
    f.u[0]=vvh; f.u[1]=vvl; f.u[2]=0; f.u[3]=0; f.u[4]=0; f.u[5]=0; f.u[6]=0; f.u[7]=0;
    AFHI[idx] = f.v;
    // B raw col (k=0..7): [-2x, 1,1, 0,0,0]
    f.u[0]=f2bf(-2.0f*p0); f.u[1]=f2bf(-2.0f*p1); f.u[2]=f2bf(-2.0f*p2);
    f.u[3]=ONE; f.u[4]=ONE; f.u[5]=0; f.u[6]=0; f.u[7]=0;
    BR[idx] = f.v;
    // B vox col (k=0..7): [0,0,0,0,0, -2u]
    f.u[0]=0; f.u[1]=0; f.u[2]=0; f.u[3]=0; f.u[4]=0;
    f.u[5]=f2bf(-2.0f*w0); f.u[6]=f2bf(-2.0f*w1); f.u[7]=f2bf(-2.0f*w2);
    BV[idx] = f.v;
    ws[OFF_XXR(g) + idx] = rr;
    ws[OFF_XXV(g) + idx] = vv;
}

// Chamfer, 32x32x16 MFMA, 4 chains/wave (64 x), __launch_bounds__(128,2)
// => 256-VGPR budget: no AGPR shuttling (the R13 regression cause).
// A rows = 32 y from global, coalesced (lane c32 -> y = base+c32, half -> lo/hi).
// B cols per chain: n<16 raw x_n, n>=16 vox x_{n-16} (verified R6-R13 layout).
// Per iter: 1 A-load + 4 MFMA + 4 min3-trees into 4 running scalars.
// Grid 2048 blocks (128 xtiles x 4 ypairs x 4 slots) x 128 thr; ysub = y*2+wave.
// Single-writer partial stores (no atomics).
__global__ void __launch_bounds__(CBLK, 2)
chamfer_kernel(float* __restrict__ ws) {
    const int tid  = threadIdx.x;
    const int wave = tid >> 6, lane = tid & 63;
    const int half = lane >> 5, c32 = lane & 31;
    const int slot = blockIdx.z;           // 0..3
    const int dir  = slot & 1;
    const int b    = slot >> 1;
    const int gX = dir*2 + b;
    const int gY = (1-dir)*2 + b;

    const short8* Abase = (const short8*)(ws + (half ? OFF_AFHI(gY) : OFF_AFLO(gY)));
    const short8* BR = (const short8*)(ws + OFF_BR(gX));
    const short8* BV = (const short8*)(ws + OFF_BV(gX));

    // 4 fused B-frags for this block's 64 x
    const int xbase = blockIdx.x * 64;
    S8 hc;   // half==1 (k=8,9): 0 for raw cols, 1.0 for vox cols (mult vvh,vvl)
    hc.u[0] = (c32 < 16) ? (unsigned short)0 : (unsigned short)0x3F80;
    hc.u[1] = hc.u[0];
    hc.u[2]=0; hc.u[3]=0; hc.u[4]=0; hc.u[5]=0; hc.u[6]=0; hc.u[7]=0;
    short8 bf[4];
#pragma unroll
    for (int f = 0; f < 4; ++f) {
        const int xi = xbase + f*16 + (c32 & 15);
        bf[f] = (half == 0) ? ((c32 < 16) ? BR[xi] : BV[xi]) : hc.v;
    }

    float mn[4];
#pragma unroll
    for (int f = 0; f < 4; ++f) mn[f] = INFINITY;

    const f16v Z = (f16v)(0.0f);
    const int ysub = blockIdx.y * 2 + wave;          // 0..7
    const int abase0 = ysub * 1024 + c32;

#pragma unroll 2
    for (int t = 0; t < 32; ++t) {                   // 32 y-tiles of 32
        const short8 a = Abase[abase0 + t*32];
#pragma unroll
        for (int f = 0; f < 4; ++f) {
            const f16v d = __builtin_amdgcn_mfma_f32_32x32x16_bf16(a, bf[f], Z, 0, 0, 0);
            const float t0 = fminf(fminf(d[0], d[1]),   fminf(d[2], d[3]));
            const float t1 = fminf(fminf(d[4], d[5]),   fminf(d[6], d[7]));
            const float t2 = fminf(fminf(d[8], d[9]),   fminf(d[10], d[11]));
            const float t3 = fminf(fminf(d[12], d[13]), fminf(d[14], d[15]));
            mn[f] = fminf(mn[f], fminf(fminf(t0, t1), fminf(t2, t3)));
        }
    }

    // other 16 rows live in the xor-32 partner lane (same column)
#pragma unroll
    for (int f = 0; f < 4; ++f)
        mn[f] = fminf(mn[f], __shfl_xor(mn[f], 32));

    if (half == 0) {
        // single writer per cell: plain stores
        const int var = (c32 < 16) ? 0 : 1;
#pragma unroll
        for (int f = 0; f < 4; ++f) {
            const int x = xbase + f*16 + (c32 & 15);
            ws[PART_IDX(ysub, slot, var, x)] = mn[f];
        }
    }
}

// 128 blocks x 256: one thread per (slot,x). Fold 8 ysubs, add |x|^2, sum, ticket-out.
__global__ void __launch_bounds__(256)
finalize_kernel(float* __restrict__ ws, float* __restrict__ out) {
    const int g = blockIdx.x * 256 + threadIdx.x;   // 0..32767
    const int slot = g >> 13;
    const int x    = g & (N-1);
    const int dir  = slot & 1;
    const int b    = slot >> 1;
    const int gX   = dir*2 + b;
    float m_r = INFINITY, m_v = INFINITY;
#pragma unroll
    for (int ys = 0; ys < 8; ++ys) {
        m_r = fminf(m_r, ws[PART_IDX(ys, slot, 0, x)]);
        m_v = fminf(m_v, ws[PART_IDX(ys, slot, 1, x)]);
    }
    float s = m_r + ws[OFF_XXR(gX) + x] + m_v + ws[OFF_XXV(gX) + x];
    for (int off = 32; off; off >>= 1)
        s += __shfl_down(s, off);
    __shared__ float sm[4];
    const int wave = threadIdx.x >> 6, lane = threadIdx.x & 63;
    if (lane == 0) sm[wave] = s;
    __syncthreads();
    if (threadIdx.x == 0) {
        const float bs = sm[0] + sm[1] + sm[2] + sm[3];
        atomicAdd(ws + WS_ACC, bs);
        __threadfence();
        const unsigned t = atomicAdd(&((unsigned*)ws)[WS_TICKET], 1u);
        if (t == gridDim.x - 1) {
            __threadfence();
            const float total = atomicAdd(ws + WS_ACC, 0.0f);  // atomic read
            out[0] = total * (1.0f / 16384.0f);
        }
    }
}

extern "C" void kernel_launch(void* const* d_in, const int* in_sizes, int n_in,
                              void* d_out, int out_size, void* d_ws, size_t ws_size,
                              hipStream_t stream) {
    const float* preds = (const float*)d_in[0];
    const float* gts   = (const float*)d_in[1];
    float* ws  = (float*)d_ws;
    float* out = (float*)d_out;

    gmin_kernel<<<dim3(4), dim3(PBLK), 0, stream>>>(preds, gts, ws);
    pack_kernel<<<dim3(128), dim3(256), 0, stream>>>(preds, gts, ws);
    chamfer_kernel<<<dim3(N/64, 4, 4), dim3(CBLK), 0, stream>>>(ws);
    finalize_kernel<<<dim3(128), dim3(256), 0, stream>>>(ws, out);
}

// Round 15
// 94.932 us; speedup vs baseline: 1.1731x; 1.0136x over previous
//
#include <hip/hip_runtime.h>
#include <math.h>

// Problem constants
#define B 2
#define N 8192            // points per batch
#define PTS_STRIDE (N*3)
#define VOXEL 0.1f

#define CBLK 128          // chamfer: 2 waves per block
#define PACKB 256

// ws layout (float offsets); ws_size >= 17 MB known, we use ~4.5 MB.
//  [16] acc   [17] ticket
//  OFF_PACK per g=arr*2+b (PERG=147456 floats):
//    AFLO[N] short8: [y0,y1,y2,yyh,yyl,w0,w1,w2]   (A rows, k=0..7)
//    AFHI[N] short8: [vvh,vvl,0,...]               (A rows, k=8..15)
//    BR[N]   short8: [-2x0,-2x1,-2x2,1,1,0,0,0]    (B raw col, k=0..7)
//    BV[N]   short8: [0,0,0,0,0,-2u0,-2u1,-2u2]    (B vox col, k=0..7)
//    XXR[N], XXV[N] f32
//  OFF_PART: float part[ysub(8)][slot(4)][var(2)][x(8192)] = 2 MB, single writer per cell
#define WS_ACC 16
#define WS_TICKET 17
#define OFF_PACK 32
#define PERG 147456
#define OFF_AFLO(g) (OFF_PACK + (g)*PERG)
#define OFF_AFHI(g) (OFF_AFLO(g) + 32768)
#define OFF_BR(g)   (OFF_AFLO(g) + 65536)
#define OFF_BV(g)   (OFF_AFLO(g) + 98304)
#define OFF_XXR(g)  (OFF_AFLO(g) + 131072)
#define OFF_XXV(g)  (OFF_AFLO(g) + 139264)
#define OFF_PART    (OFF_PACK + 4*PERG)
#define PART_IDX(ys, slot, var, x) (OFF_PART + (((((ys)*4 + (slot))*2 + (var)) << 13)) + (x))

typedef __attribute__((ext_vector_type(8))) short short8;    // 8 bf16 (MFMA A/B frag)
typedef __attribute__((ext_vector_type(16))) float f16v;     // 32x32 MFMA C/D frag

union S8 { short8 v; unsigned short u[8]; };

__device__ __forceinline__ unsigned short f2bf(float f) {    // RNE f32->bf16
    unsigned u = __float_as_uint(f);
    return (unsigned short)((u + 0x7FFFu + ((u >> 16) & 1u)) >> 16);
}
__device__ __forceinline__ float bf2f(unsigned short h) {
    return __uint_as_float(((unsigned)h) << 16);
}
__device__ __forceinline__ float voxq(float v, float g) {
    return (float)(int)((v - g) / VOXEL);   // trunc like .astype(int32)
}

// 128 blocks x 256: g = bid>>5, chunk = bid&31. Each block redundantly
// computes the batch gmin (vectorized, L2-hit after first block), then
// packs its 256-point chunk. Fuses the old gmin+pack launches.
__global__ void __launch_bounds__(PACKB)
pack_kernel(const float* __restrict__ preds,
            const float* __restrict__ gts,
            float* __restrict__ ws) {
    const int g     = blockIdx.x >> 5;       // 0..3 = arr*2+b
    const int chunk = blockIdx.x & 31;       // 0..31
    const int arr = g >> 1;
    const int b   = g & 1;
    const float* base = (arr ? gts : preds) + b * PTS_STRIDE;
    const float4* base4 = (const float4*)base;

    // --- redundant gmin over the whole batch (NaN -> inf) ---
    float m0 = INFINITY, m1 = INFINITY, m2 = INFINITY;
#pragma unroll 2
    for (int j = 0; j < 8; ++j) {
        const int i = j * PACKB + threadIdx.x;    // 0..2047, 4 points each
        const float4 q0 = base4[i*3+0];   // p0x p0y p0z p1x
        const float4 q1 = base4[i*3+1];   // p1y p1z p2x p2y
        const float4 q2 = base4[i*3+2];   // p2z p3x p3y p3z
        float v;
        v = q0.x; m0 = fminf(m0, (v!=v)?INFINITY:v);
        v = q0.w; m0 = fminf(m0, (v!=v)?INFINITY:v);
        v = q1.z; m0 = fminf(m0, (v!=v)?INFINITY:v);
        v = q2.y; m0 = fminf(m0, (v!=v)?INFINITY:v);
        v = q0.y; m1 = fminf(m1, (v!=v)?INFINITY:v);
        v = q1.x; m1 = fminf(m1, (v!=v)?INFINITY:v);
        v = q1.w; m1 = fminf(m1, (v!=v)?INFINITY:v);
        v = q2.z; m1 = fminf(m1, (v!=v)?INFINITY:v);
        v = q0.z; m2 = fminf(m2, (v!=v)?INFINITY:v);
        v = q1.y; m2 = fminf(m2, (v!=v)?INFINITY:v);
        v = q2.x; m2 = fminf(m2, (v!=v)?INFINITY:v);
        v = q2.w; m2 = fminf(m2, (v!=v)?INFINITY:v);
    }
    for (int off = 32; off; off >>= 1) {
        m0 = fminf(m0, __shfl_down(m0, off));
        m1 = fminf(m1, __shfl_down(m1, off));
        m2 = fminf(m2, __shfl_down(m2, off));
    }
    __shared__ float sm[4][3];
    __shared__ float gsh[3];
    const int wave = threadIdx.x >> 6, lane = threadIdx.x & 63;
    if (lane == 0) { sm[wave][0] = m0; sm[wave][1] = m1; sm[wave][2] = m2; }
    __syncthreads();
    if (threadIdx.x == 0) {
        gsh[0] = fminf(fminf(sm[0][0], sm[1][0]), fminf(sm[2][0], sm[3][0]));
        gsh[1] = fminf(fminf(sm[0][1], sm[1][1]), fminf(sm[2][1], sm[3][1]));
        gsh[2] = fminf(fminf(sm[0][2], sm[1][2]), fminf(sm[2][2], sm[3][2]));
        if (blockIdx.x == 0) { ws[WS_ACC] = 0.0f; ((unsigned*)ws)[WS_TICKET] = 0u; }
    }
    __syncthreads();
    const float g0 = gsh[0], g1 = gsh[1], g2 = gsh[2];

    // --- pack this chunk's 256 points (one per thread) ---
    const int idx = chunk * PACKB + threadIdx.x;
    const float p0 = base[idx*3+0], p1 = base[idx*3+1], p2 = base[idx*3+2];
    const float w0 = voxq(p0, g0), w1 = voxq(p1, g1), w2 = voxq(p2, g2);
    const float rr = fmaf(p0,p0, fmaf(p1,p1, p2*p2));
    const float vv = fmaf(w0,w0, fmaf(w1,w1, w2*w2));

    const unsigned short yyh = f2bf(rr);
    const unsigned short yyl = f2bf(rr - bf2f(yyh));
    const unsigned short vvh = f2bf(vv);
    const unsigned short vvl = f2bf(vv - bf2f(vvh));
    const unsigned short ONE = 0x3F80;

    short8* AFLO = (short8*)(ws + OFF_AFLO(g));
    short8* AFHI = (short8*)(ws + OFF_AFHI(g));
    short8* BR   = (short8*)(ws + OFF_BR(g));
    short8* BV   = (short8*)(ws + OFF_BV(g));

    S8 f;
    // A lo (k=0..7): [y0,y1,y2,yyh,yyl, w0,w1,w2]
    f.u[0]=f2bf(p0); f.u[1]=f2bf(p1); f.u[2]=f2bf(p2);
    f.u[3]=yyh; f.u[4]=yyl; f.u[5]=f2bf(w0); f.u[6]=f2bf(w1); f.u[7]=f2bf(w2);
    AFLO[idx] = f.v;
    // A hi (k=8..15): [vvh,vvl,0...]
    f.u[0]=vvh; f.u[1]=vvl; f.u[2]=0; f.u[3]=0; f.u[4]=0; f.u[5]=0; f.u[6]=0; f.u[7]=0;
    AFHI[idx] = f.v;
    // B raw col (k=0..7): [-2x, 1,1, 0,0,0]
    f.u[0]=f2bf(-2.0f*p0); f.u[1]=f2bf(-2.0f*p1); f.u[2]=f2bf(-2.0f*p2);
    f.u[3]=ONE; f.u[4]=ONE; f.u[5]=0; f.u[6]=0; f.u[7]=0;
    BR[idx] = f.v;
    // B vox col (k=0..7): [0,0,0,0,0, -2u]
    f.u[0]=0; f.u[1]=0; f.u[2]=0; f.u[3]=0; f.u[4]=0;
    f.u[5]=f2bf(-2.0f*w0); f.u[6]=f2bf(-2.0f*w1); f.u[7]=f2bf(-2.0f*w2);
    BV[idx] = f.v;
    ws[OFF_XXR(g) + idx] = rr;
    ws[OFF_XXV(g) + idx] = vv;
}

// Chamfer = the best-measured R10 config (2 chains, launch_bounds(128,6),
// 4096 blocks), with single-writer partial stores instead of atomicMin.
// A rows = 32 y from global, coalesced; B cols: n<16 raw x_n, n>=16 vox.
// ysub = blockIdx.y*2 + wave covers 1024 y. No LDS, no barriers, no atomics.
__global__ void __launch_bounds__(CBLK, 6)
chamfer_kernel(float* __restrict__ ws) {
    const int tid  = threadIdx.x;
    const int wave = tid >> 6, lane = tid & 63;
    const int half = lane >> 5, c32 = lane & 31;
    const int slot = blockIdx.z;           // 0..3
    const int dir  = slot & 1;
    const int b    = slot >> 1;
    const int gX = dir*2 + b;
    const int gY = (1-dir)*2 + b;

    const short8* Abase = (const short8*)(ws + (half ? OFF_AFHI(gY) : OFF_AFLO(gY)));
    const short8* BR = (const short8*)(ws + OFF_BR(gX));
    const short8* BV = (const short8*)(ws + OFF_BV(gX));

    // 2 fused B-frags for this block's 32 x
    const int xbase = blockIdx.x * 32;
    S8 hc;   // half==1 (k=8,9): 0 for raw cols, 1.0 for vox cols
    hc.u[0] = (c32 < 16) ? (unsigned short)0 : (unsigned short)0x3F80;
    hc.u[1] = hc.u[0];
    hc.u[2]=0; hc.u[3]=0; hc.u[4]=0; hc.u[5]=0; hc.u[6]=0; hc.u[7]=0;
    const int xcol0 = xbase + (c32 & 15);
    const short8 bf0 = (half == 0) ? ((c32 < 16) ? BR[xcol0] : BV[xcol0]) : hc.v;
    const short8 bf1 = (half == 0) ? ((c32 < 16) ? BR[xcol0+16] : BV[xcol0+16]) : hc.v;

    float mn0 = INFINITY, mn1 = INFINITY;
    const f16v Z = (f16v)(0.0f);
    const int ysub = blockIdx.y * 2 + wave;         // 0..7
    const int abase0 = ysub * 1024 + c32;

#pragma unroll 2
    for (int t = 0; t < 32; ++t) {                  // 32 y-tiles of 32
        const short8 a = Abase[abase0 + t*32];
        const f16v d0 = __builtin_amdgcn_mfma_f32_32x32x16_bf16(a, bf0, Z, 0, 0, 0);
        {
            const float t0 = fminf(fminf(d0[0], d0[1]),   fminf(d0[2], d0[3]));
            const float t1 = fminf(fminf(d0[4], d0[5]),   fminf(d0[6], d0[7]));
            const float t2 = fminf(fminf(d0[8], d0[9]),   fminf(d0[10], d0[11]));
            const float t3 = fminf(fminf(d0[12], d0[13]), fminf(d0[14], d0[15]));
            mn0 = fminf(mn0, fminf(fminf(t0, t1), fminf(t2, t3)));
        }
        const f16v d1 = __builtin_amdgcn_mfma_f32_32x32x16_bf16(a, bf1, Z, 0, 0, 0);
        {
            const float t0 = fminf(fminf(d1[0], d1[1]),   fminf(d1[2], d1[3]));
            const float t1 = fminf(fminf(d1[4], d1[5]),   fminf(d1[6], d1[7]));
            const float t2 = fminf(fminf(d1[8], d1[9]),   fminf(d1[10], d1[11]));
            const float t3 = fminf(fminf(d1[12], d1[13]), fminf(d1[14], d1[15]));
            mn1 = fminf(mn1, fminf(fminf(t0, t1), fminf(t2, t3)));
        }
    }

    // other 16 rows live in the xor-32 partner lane (same column)
    mn0 = fminf(mn0, __shfl_xor(mn0, 32));
    mn1 = fminf(mn1, __shfl_xor(mn1, 32));

    if (half == 0) {
        // single writer per cell: plain coalesced stores, no atomics
        const int var = (c32 < 16) ? 0 : 1;
        ws[PART_IDX(ysub, slot, var, xcol0)]      = mn0;
        ws[PART_IDX(ysub, slot, var, xcol0 + 16)] = mn1;
    }
}

// 128 blocks x 256: one thread per (slot,x). Fold 8 ysubs, add |x|^2, sum, ticket-out.
__global__ void __launch_bounds__(256)
finalize_kernel(float* __restrict__ ws, float* __restrict__ out) {
    const int g = blockIdx.x * 256 + threadIdx.x;   // 0..32767
    const int slot = g >> 13;
    const int x    = g & (N-1);
    const int dir  = slot & 1;
    const int b    = slot >> 1;
    const int gX   = dir*2 + b;
    float m_r = INFINITY, m_v = INFINITY;
#pragma unroll
    for (int ys = 0; ys < 8; ++ys) {
        m_r = fminf(m_r, ws[PART_IDX(ys, slot, 0, x)]);
        m_v = fminf(m_v, ws[PART_IDX(ys, slot, 1, x)]);
    }
    float s = m_r + ws[OFF_XXR(gX) + x] + m_v + ws[OFF_XXV(gX) + x];
    for (int off = 32; off; off >>= 1)
        s += __shfl_down(s, off);
    __shared__ float sm[4];
    const int wave = threadIdx.x >> 6, lane = threadIdx.x & 63;
    if (lane == 0) sm[wave] = s;
    __syncthreads();
    if (threadIdx.x == 0) {
        const float bs = sm[0] + sm[1] + sm[2] + sm[3];
        atomicAdd(ws + WS_ACC, bs);
        __threadfence();
        const unsigned t = atomicAdd(&((unsigned*)ws)[WS_TICKET], 1u);
        if (t == gridDim.x - 1) {
            __threadfence();
            const float total = atomicAdd(ws + WS_ACC, 0.0f);  // atomic read
            out[0] = total * (1.0f / 16384.0f);
        }
    }
}

extern "C" void kernel_launch(void* const* d_in, const int* in_sizes, int n_in,
                              void* d_out, int out_size, void* d_ws, size_t ws_size,
                              hipStream_t stream) {
    const float* preds = (const float*)d_in[0];
    const float* gts   = (const float*)d_in[1];
    float* ws  = (float*)d_ws;
    float* out = (float*)d_out;

    pack_kernel<<<dim3(128), dim3(PACKB), 0, stream>>>(preds, gts, ws);
    chamfer_kernel<<<dim3(N/32, 4, 4), dim3(CBLK), 0, stream>>>(ws);
    finalize_kernel<<<dim3(128), dim3(256), 0, stream>>>(ws, out);
}